// Round 10
// baseline (98.110 us; speedup 1.0000x reference)
//
#include <hip/hip_runtime.h>
#include <math.h>

// Problem constants (fixed by setup_inputs)
#define BB 4
#define DD 256
#define NN 65536      // H*W
#define CC 16
#define PP 5
#define CP 80         // C*P
#define EPSV 1e-10f
#define PBYTES 272    // proto chunk row pitch in bytes (128 bf16 + pad -> 16B aligned)

// ws layout (floats):
//   protosN : [0, 20480)
//   plane   : [20480, +B*P*N)   holds e1 = exp(sim-1)
//   acc     : denom1[320] denom2[320] cnt[64] Bbins[B*C*16]
#define OFF_PLANE  20480
#define OFF_ACC    (OFF_PLANE + BB * PP * NN)
#define ACC_FLOATS (320 + 320 + 64 + BB * CC * 16)

__device__ __forceinline__ unsigned int f2bf(float f) {
    unsigned int u = __float_as_uint(f);
    u += 0x7fffu + ((u >> 16) & 1u);      // RNE
    return u >> 16;
}

// async global->LDS, 16B per lane (LDS dest = uniform base + lane*16)
__device__ __forceinline__ void gload_lds16(const float* g, void* l) {
    __builtin_amdgcn_global_load_lds(
        (const __attribute__((address_space(1))) unsigned int*)g,
        (__attribute__((address_space(3))) unsigned int*)l, 16, 0, 0);
}

// blocks 0..79: normalize prototype rows; block 80: zero accumulators
__global__ void k_norm(const float* __restrict__ protos,
                       float* __restrict__ protosN,
                       float* __restrict__ acc) {
    if (blockIdx.x == CP) {
        for (int i = threadIdx.x; i < ACC_FLOATS; i += 256) acc[i] = 0.f;
        return;
    }
    int r = blockIdx.x;
    int d = threadIdx.x;
    float v = protos[r * DD + d];
    __shared__ float red[256];
    red[d] = v * v;
    __syncthreads();
    for (int s = 128; s > 0; s >>= 1) {
        if (d < s) red[d] += red[d + s];
        __syncthreads();
    }
    float inv = 1.f / fmaxf(sqrtf(red[0]), 1e-12f);
    protosN[r * DD + d] = v * inv;
}

// consume one staged 8-d group for 2 px: protos from lpp chunk, fmap from fstage
__device__ __forceinline__ void comp(const char* lb0, const char* lb1,
                                     const float2 (&f)[8], int g,
                                     float (&d0)[PP], float (&d1)[PP],
                                     float& n0, float& n1) {
    uint4 q0[PP], q1[PP];
    #pragma unroll
    for (int p = 0; p < PP; ++p) {
        q0[p] = *reinterpret_cast<const uint4*>(lb0 + p * PBYTES + g * 16);
        q1[p] = *reinterpret_cast<const uint4*>(lb1 + p * PBYTES + g * 16);
    }
    #pragma unroll
    for (int k = 0; k < 8; ++k) {
        float fx = f[k].x, fy = f[k].y;
        n0 = fmaf(fx, fx, n0);
        n1 = fmaf(fy, fy, n1);
        #pragma unroll
        for (int p = 0; p < PP; ++p) {
            unsigned int w0 = (&q0[p].x)[k >> 1];
            unsigned int w1 = (&q1[p].x)[k >> 1];
            float a = __uint_as_float((k & 1) ? (w0 & 0xffff0000u) : (w0 << 16));
            float c = __uint_as_float((k & 1) ? (w1 & 0xffff0000u) : (w1 << 16));
            d0[p] = fmaf(fx, a, d0[p]);
            d1[p] = fmaf(fy, c, d1[p]);
        }
    }
}

// Pass 1: R4 skeleton (2 px/thread, grid 512x256, bf16 protos in LDS) but the
// fmap read goes through async global_load_lds into wave-private double-buffered
// LDS staging (counted vmcnt, no barriers in the main loop) to test whether the
// direct-to-LDS path tracks more outstanding requests than the VGPR-return path.
__global__ __launch_bounds__(256) void k_sims(const float* __restrict__ fmap,
                                              const float* __restrict__ protosN,
                                              const int* __restrict__ gt,
                                              float* __restrict__ plane,
                                              float* __restrict__ denom1,
                                              float* __restrict__ cnt) {
    __shared__ __align__(16) unsigned short lpp[CP * (PBYTES / 2)];   // 21760 B
    __shared__ __align__(16) char fstage[4][2][4096];                 // 32768 B
    __shared__ float bins[CP];
    __shared__ float binc[CC];
    const int tid  = threadIdx.x;
    const int wave = tid >> 6;
    const int lane = tid & 63;
    const int b    = blockIdx.x >> 7;                 // 512 blocks: 128/batch
    const int N0   = (blockIdx.x & 127) << 9;         // block's 512-px base
    const int n0   = N0 + (tid << 1);                 // this thread's 2 px
    const int nw   = N0 + (wave << 7);                // wave's 128-px base

    if (tid < CP) bins[tid] = 0.f;
    if (tid < CC) binc[tid] = 0.f;

    const int2 cls = *reinterpret_cast<const int2*>(&gt[(size_t)b * NN + n0]);
    const float* fwb = fmap + (size_t)b * DD * NN + nw;   // wave's fmap base
    // per-lane staging address pieces: row = d0 + (lane>>5), col = (lane&31)*4
    const int lrow = lane >> 5;
    const int lcol = (lane & 31) << 2;

    float dot0[PP] = {0.f, 0.f, 0.f, 0.f, 0.f};
    float dot1[PP] = {0.f, 0.f, 0.f, 0.f, 0.f};
    float nrm0 = 0.f, nrm1 = 0.f;

    #pragma unroll 1
    for (int ch = 0; ch < 2; ++ch) {
        __syncthreads();   // protect lpp reuse (also drains pipes at chunk edge)
        // load proto chunk ch (128 d's) f32 -> bf16 into lpp
        #pragma unroll 1
        for (int it = 0; it < 10; ++it) {
            int idx = tid + (it << 8);                // 0..2559 float4s
            int cp = idx >> 5, q = idx & 31;
            float4 v = *reinterpret_cast<const float4*>(
                &protosN[(cp << 8) + (ch << 7) + (q << 2)]);
            unsigned int u0 = f2bf(v.x) | (f2bf(v.y) << 16);
            unsigned int u1 = f2bf(v.z) | (f2bf(v.w) << 16);
            *reinterpret_cast<uint2*>(reinterpret_cast<char*>(lpp) + cp * PBYTES + (q << 3))
                = make_uint2(u0, u1);
        }
        __syncthreads();

        const char* lb0 = reinterpret_cast<const char*>(lpp) + cls.x * (PP * PBYTES);
        const char* lb1 = reinterpret_cast<const char*>(lpp) + cls.y * (PP * PBYTES);
        const int dbase = ch << 7;

        // prologue: stage groups 0 and 1 of this chunk (4 instrs each)
        #pragma unroll
        for (int i = 0; i < 4; ++i)
            gload_lds16(fwb + (size_t)(dbase + 2 * i + lrow) * NN + lcol,
                        &fstage[wave][0][i * 1024]);
        #pragma unroll
        for (int i = 0; i < 4; ++i)
            gload_lds16(fwb + (size_t)(dbase + 8 + 2 * i + lrow) * NN + lcol,
                        &fstage[wave][1][i * 1024]);

        #pragma unroll 1
        for (int g = 0; g < 16; ++g) {
            if (g < 15) asm volatile("s_waitcnt vmcnt(4)" ::: "memory");
            else        asm volatile("s_waitcnt vmcnt(0)" ::: "memory");
            const char* fs = &fstage[wave][g & 1][0];
            float2 f[8];
            #pragma unroll
            for (int i = 0; i < 8; ++i)
                f[i] = *reinterpret_cast<const float2*>(fs + i * 512 + (lane << 3));
            // reads must complete before re-staging the same buffer
            asm volatile("s_waitcnt lgkmcnt(0)" ::: "memory");
            if (g < 14) {
                const int d0 = dbase + (g + 2) * 8;
                #pragma unroll
                for (int i = 0; i < 4; ++i)
                    gload_lds16(fwb + (size_t)(d0 + 2 * i + lrow) * NN + lcol,
                                &fstage[wave][g & 1][i * 1024]);
            }
            comp(lb0, lb1, f, g, dot0, dot1, nrm0, nrm1);
        }
    }

    const float inv0 = 1.f / fmaxf(sqrtf(nrm0), 1e-12f);
    const float inv1 = 1.f / fmaxf(sqrtf(nrm1), 1e-12f);
    #pragma unroll
    for (int p = 0; p < PP; ++p) {
        float2 e;
        e.x = __expf(dot0[p] * inv0 - 1.f);   // fixed shift: sims in [-1,1]
        e.y = __expf(dot1[p] * inv1 - 1.f);
        *reinterpret_cast<float2*>(&plane[(size_t)(b * PP + p) * NN + n0]) = e;
        atomicAdd(&bins[cls.x * PP + p], e.x);
        atomicAdd(&bins[cls.y * PP + p], e.y);
    }
    atomicAdd(&binc[cls.x], 1.f);
    atomicAdd(&binc[cls.y], 1.f);
    __syncthreads();
    if (tid < CP) atomicAdd(&denom1[b * CP + tid], bins[tid]);
    if (tid < CC) atomicAdd(&cnt[b * CC + tid], binc[tid]);
}

// Pass 2 (read-only): u = exp(e1/denom1 - 1); denom2 += u.  4 px/thread.
__global__ __launch_bounds__(256) void k_denom2(const int* __restrict__ gt,
                                                const float* __restrict__ plane,
                                                const float* __restrict__ denom1,
                                                float* __restrict__ denom2) {
    __shared__ float inv1s[CP];
    __shared__ float bins[4][CP];          // replicated per warp
    const int tid = threadIdx.x;
    const int w   = tid >> 6;
    const int b   = blockIdx.x >> 6;       // 256 blocks: 64/batch
    const int n0  = ((blockIdx.x & 63) << 10) + (tid << 2);
    if (tid < CP) inv1s[tid] = 1.f / denom1[b * CP + tid];
    for (int i = tid; i < 4 * CP; i += 256) (&bins[0][0])[i] = 0.f;
    __syncthreads();
    const int4 cls = *reinterpret_cast<const int4*>(&gt[(size_t)b * NN + n0]);
    #pragma unroll
    for (int p = 0; p < PP; ++p) {
        size_t idx = (size_t)(b * PP + p) * NN + n0;
        float4 e = *reinterpret_cast<const float4*>(&plane[idx]);
        atomicAdd(&bins[w][cls.x * PP + p], __expf(e.x * inv1s[cls.x * PP + p] - 1.f));
        atomicAdd(&bins[w][cls.y * PP + p], __expf(e.y * inv1s[cls.y * PP + p] - 1.f));
        atomicAdd(&bins[w][cls.z * PP + p], __expf(e.z * inv1s[cls.z * PP + p] - 1.f));
        atomicAdd(&bins[w][cls.w * PP + p], __expf(e.w * inv1s[cls.w * PP + p] - 1.f));
    }
    __syncthreads();
    if (tid < CP)
        atomicAdd(&denom2[b * CP + tid],
                  bins[0][tid] + bins[1][tid] + bins[2][tid] + bins[3][tid]);
}

// Pass 3: recompute u from e1 (bit-identical), V = u/denom2 + EPS;
// accumulate A_i (5) and S_ij = L_iV_j + L_jV_i (10) per (b,c).
__global__ __launch_bounds__(256) void k_bmat(const int* __restrict__ gt,
                                              const float* __restrict__ plane,
                                              const float* __restrict__ denom1,
                                              const float* __restrict__ denom2,
                                              float* __restrict__ Bbins) {
    __shared__ float inv1s[CP];
    __shared__ float inv2s[CP];
    __shared__ float sb[4][CC * 16];       // replicated per warp
    const int tid = threadIdx.x;
    const int w   = tid >> 6;
    const int b   = blockIdx.x >> 6;
    const int n0  = ((blockIdx.x & 63) << 10) + (tid << 2);
    if (tid < CP) {
        inv1s[tid] = 1.f / denom1[b * CP + tid];
        inv2s[tid] = 1.f / denom2[b * CP + tid];
    }
    for (int i = tid; i < 4 * CC * 16; i += 256) (&sb[0][0])[i] = 0.f;
    __syncthreads();
    const int4 cls = *reinterpret_cast<const int4*>(&gt[(size_t)b * NN + n0]);
    const int c4[4] = {cls.x, cls.y, cls.z, cls.w};
    float V[4][PP], L[4][PP];
    #pragma unroll
    for (int p = 0; p < PP; ++p) {
        size_t idx = (size_t)(b * PP + p) * NN + n0;
        float4 e = *reinterpret_cast<const float4*>(&plane[idx]);
        V[0][p] = fmaf(__expf(e.x * inv1s[cls.x * PP + p] - 1.f), inv2s[cls.x * PP + p], EPSV);
        V[1][p] = fmaf(__expf(e.y * inv1s[cls.y * PP + p] - 1.f), inv2s[cls.y * PP + p], EPSV);
        V[2][p] = fmaf(__expf(e.z * inv1s[cls.z * PP + p] - 1.f), inv2s[cls.z * PP + p], EPSV);
        V[3][p] = fmaf(__expf(e.w * inv1s[cls.w * PP + p] - 1.f), inv2s[cls.w * PP + p], EPSV);
    }
    #pragma unroll
    for (int q = 0; q < 4; ++q)
        #pragma unroll
        for (int p = 0; p < PP; ++p) L[q][p] = __logf(V[q][p]);
    #pragma unroll
    for (int q = 0; q < 4; ++q) {
        float* base = &sb[w][c4[q] * 16];
        #pragma unroll
        for (int i = 0; i < PP; ++i) atomicAdd(&base[i], L[q][i] * V[q][i]);
        int slot = 5;
        #pragma unroll
        for (int i = 0; i < PP; ++i)
            #pragma unroll
            for (int j = i + 1; j < PP; ++j) {
                atomicAdd(&base[slot], fmaf(L[q][i], V[q][j], L[q][j] * V[q][i]));
                ++slot;
            }
    }
    __syncthreads();
    for (int i = tid; i < CC * 16; i += 256)
        atomicAdd(&Bbins[b * CC * 16 + i], sb[0][i] + sb[1][i] + sb[2][i] + sb[3][i]);
}

__global__ void k_final(const float* __restrict__ Bbins,
                        const float* __restrict__ cnt,
                        float* __restrict__ out) {
    __shared__ float cs[BB * CC];
    __shared__ float pr[BB * CC];
    const int t = threadIdx.x;
    if (t < BB * CC) {
        const float* bb = &Bbins[t * 16];
        float s = 0.f;
        int slot = 5;
        #pragma unroll
        for (int i = 0; i < PP; ++i)
            for (int j = i + 1; j < PP; ++j) {
                float J = bb[i] + bb[j] - bb[slot];   // A_i + A_j - S_ij
                ++slot;
                s += __expf(-J);
            }
        bool present = cnt[t] > 0.f;
        cs[t] = present ? s * 0.1f : 0.f;   // / num_pairs (=10)
        pr[t] = present ? 1.f : 0.f;
    }
    __syncthreads();
    if (t == 0) {
        float total = 0.f;
        for (int b = 0; b < BB; ++b) {
            float sc = 0.f, np = 0.f;
            for (int c = 0; c < CC; ++c) { sc += cs[b * CC + c]; np += pr[b * CC + c]; }
            total += (np > 0.f) ? sc / np : 0.f;
        }
        out[0] = total / (float)BB;
    }
}

extern "C" void kernel_launch(void* const* d_in, const int* in_sizes, int n_in,
                              void* d_out, int out_size, void* d_ws, size_t ws_size,
                              hipStream_t stream) {
    const float* fmap   = (const float*)d_in[0];
    const float* protos = (const float*)d_in[1];
    const int*   gt     = (const int*)d_in[2];
    float* ws      = (float*)d_ws;
    float* protosN = ws;
    float* plane   = ws + OFF_PLANE;
    float* acc     = ws + OFF_ACC;
    float* denom1  = acc;
    float* denom2  = acc + 320;
    float* cnt     = acc + 640;
    float* Bbins   = acc + 704;
    float* out     = (float*)d_out;

    k_norm  <<<CP + 1, 256, 0, stream>>>(protos, protosN, acc);
    k_sims  <<<512, 256, 0, stream>>>(fmap, protosN, gt, plane, denom1, cnt);
    k_denom2<<<256, 256, 0, stream>>>(gt, plane, denom1, denom2);
    k_bmat  <<<256, 256, 0, stream>>>(gt, plane, denom1, denom2, Bbins);
    k_final <<<1, 64, 0, stream>>>(Bbins, cnt, out);
}